// Round 4
// baseline (17.349 us; speedup 1.0000x reference)
//
#include <hip/hip_runtime.h>

#define NATOMS 25000
#define NSP 64
#define NRANGE 8
#define RSIZE ((NATOMS + NRANGE - 1) / NRANGE)   // 3125 atoms per range
#define WSUB ((RSIZE + 3) / 4)                   // 782 atoms per wave
#define WIT ((WSUB + 63) / 64)                   // 13 scan iters per wave
#define LCAP (WIT * 64)                          // 832 list capacity

typedef short bf16x8 __attribute__((ext_vector_type(8)));   // 8 bf16 = 4 VGPRs
typedef float f32x4  __attribute__((ext_vector_type(4)));
typedef unsigned short u16;

// f32 -> bf16 round-to-nearest-even
__device__ __forceinline__ u16 f2bf(float f) {
  unsigned u = __float_as_uint(f);
  u += 0x7fffu + ((u >> 16) & 1u);
  return (u16)(u >> 16);
}

__global__ __launch_bounds__(256)
void zcl_kernel(const float* __restrict__ feat,
                const int*   __restrict__ sp,
                const float* __restrict__ weight,
                const float* __restrict__ bias,
                float*       __restrict__ out)
{
  // W[o][i] bf16, rows of 128; 16B chunks XOR-swizzled by (row&7): B-frag
  // ds_read_b128 then hits the 8-slot/bank floor exactly (even spread).
  __shared__ u16 Ws[128 * 128];      // 32 KiB
  __shared__ u16 wlist[4][LCAP];     // 6.5 KiB, wave-private segments

  const int tid = threadIdx.x;
  const int bid = blockIdx.x;
  const int s  = bid >> 3;           // species
  const int r  = bid & 7;            // atom range
  const int lo = r * RSIZE;
  const int hi = (lo + RSIZE < NATOMS) ? (lo + RSIZE) : NATOMS;

  const int wv   = tid >> 6;
  const int lane = tid & 63;
  const int l16  = lane & 15;
  const int kq   = lane >> 4;
  const int wlo  = lo + wv * WSUB;   // wave-private sub-range
  const int whi  = (wlo + WSUB < hi) ? (wlo + WSUB) : hi;

  // ---- 1) issue sp preload FIRST (oldest in VMEM queue -> completes first) ----
  int spv[WIT];
  #pragma unroll
  for (int i = 0; i < WIT; ++i) {
    int a = wlo + i * 64 + lane;
    spv[i] = (a < whi) ? sp[a] : -1;
  }

  // bias hoist (L2-hot)
  float bvb[8];
  #pragma unroll
  for (int nf = 0; nf < 8; ++nf) bvb[nf] = bias[s * 128 + l16 + 16 * nf];

  // ---- 2) issue W[s] f32 loads (16 float4/thread, stay in flight) ----
  const float4* wg = (const float4*)(weight + (size_t)s * (128 * 128));
  float4 w0[8], w1[8];
  #pragma unroll
  for (int j = 0; j < 8; ++j) {
    int m = j * 256 + tid;           // chunk: row = m>>4, 8-elem group c = m&15
    int row = m >> 4, c = m & 15;
    w0[j] = wg[row * 32 + c * 2];
    w1[j] = wg[row * 32 + c * 2 + 1];
  }

  // ---- 3) wave-private compact scan: no atomics, no barriers ----
  int wcnt = 0;
  #pragma unroll
  for (int i = 0; i < WIT; ++i) {
    bool m = (spv[i] == s);
    unsigned long long mk = __ballot(m);
    if (m) wlist[wv][wcnt + __popcll(mk & ((1ull << lane) - 1ull))] =
             (u16)(wlo + i * 64 + lane);
    wcnt += (int)__popcll(mk);
  }
  const int nt = (wcnt + 15) >> 4;

  // ---- 4) prefetch A for this wave's tile 0 (overlaps W arrival) ----
  float4 pf[8];
  if (nt > 0) {
    int li = l16;
    int atomA = wlist[wv][li < wcnt ? li : 0];
    const float4* xg = (const float4*)(feat + (size_t)atomA * 128);
    #pragma unroll
    for (int ks = 0; ks < 4; ++ks) {
      pf[2 * ks]     = xg[ks * 8 + kq * 2];
      pf[2 * ks + 1] = xg[ks * 8 + kq * 2 + 1];
    }
  }

  // ---- 5) convert W -> bf16, swizzled ds_write (fine-grained vmcnt per j) ----
  #pragma unroll
  for (int j = 0; j < 8; ++j) {
    int m = j * 256 + tid;
    int row = m >> 4, c = m & 15;
    union { u16 h[8]; bf16x8 v; } uu;
    uu.h[0] = f2bf(w0[j].x); uu.h[1] = f2bf(w0[j].y);
    uu.h[2] = f2bf(w0[j].z); uu.h[3] = f2bf(w0[j].w);
    uu.h[4] = f2bf(w1[j].x); uu.h[5] = f2bf(w1[j].y);
    uu.h[6] = f2bf(w1[j].z); uu.h[7] = f2bf(w1[j].w);
    *(bf16x8*)&Ws[row * 128 + ((c ^ (row & 7)) << 3)] = uu.v;
  }

  __syncthreads();   // Ws visible to all waves

  // ---- 6) wave-independent tile loop (16 atoms x 128 outs x K=128) ----
  for (int t = 0; t < nt; ++t) {
    // convert current A (consumes pf) BEFORE issuing next prefetch
    bf16x8 av[4];
    #pragma unroll
    for (int ks = 0; ks < 4; ++ks) {
      union { u16 h[8]; bf16x8 v; } uu;
      uu.h[0] = f2bf(pf[2 * ks].x);     uu.h[1] = f2bf(pf[2 * ks].y);
      uu.h[2] = f2bf(pf[2 * ks].z);     uu.h[3] = f2bf(pf[2 * ks].w);
      uu.h[4] = f2bf(pf[2 * ks + 1].x); uu.h[5] = f2bf(pf[2 * ks + 1].y);
      uu.h[6] = f2bf(pf[2 * ks + 1].z); uu.h[7] = f2bf(pf[2 * ks + 1].w);
      av[ks] = uu.v;
    }

    if (t + 1 < nt) {   // prefetch next tile (overlaps MFMA + stores)
      int li = (t + 1) * 16 + l16;
      int atomA = wlist[wv][li < wcnt ? li : 0];
      const float4* xg = (const float4*)(feat + (size_t)atomA * 128);
      #pragma unroll
      for (int ks = 0; ks < 4; ++ks) {
        pf[2 * ks]     = xg[ks * 8 + kq * 2];
        pf[2 * ks + 1] = xg[ks * 8 + kq * 2 + 1];
      }
    }

    f32x4 acc[8];
    #pragma unroll
    for (int nf = 0; nf < 8; ++nf) acc[nf] = (f32x4){0.f, 0.f, 0.f, 0.f};
    #pragma unroll
    for (int ks = 0; ks < 4; ++ks) {
      int chunk = ((ks * 4 + kq) ^ (l16 & 7)) << 3;
      #pragma unroll
      for (int nf = 0; nf < 8; ++nf) {
        bf16x8 b = *(const bf16x8*)&Ws[(l16 + 16 * nf) * 128 + chunk];
        acc[nf] = __builtin_amdgcn_mfma_f32_16x16x32_bf16(av[ks], b, acc[nf], 0, 0, 0);
      }
    }

    // store: D row(m) = kq*4+q -> atom; col = l16 -> out l16+16*nf
    #pragma unroll
    for (int q = 0; q < 4; ++q) {
      int li2 = t * 16 + kq * 4 + q;
      if (li2 < wcnt) {
        int atom = wlist[wv][li2];
        float* op = out + (size_t)atom * 128 + l16;
        #pragma unroll
        for (int nf = 0; nf < 8; ++nf) op[16 * nf] = acc[nf][q] + bvb[nf];
      }
    }
  }
}

extern "C" void kernel_launch(void* const* d_in, const int* in_sizes, int n_in,
                              void* d_out, int out_size, void* d_ws, size_t ws_size,
                              hipStream_t stream) {
  const float* feat   = (const float*)d_in[0];
  const int*   sp     = (const int*)d_in[1];
  const float* weight = (const float*)d_in[2];
  const float* bias   = (const float*)d_in[3];
  float*       out    = (float*)d_out;
  zcl_kernel<<<NSP * NRANGE, 256, 0, stream>>>(feat, sp, weight, bias, out);
}